// Round 4
// baseline (283.743 us; speedup 1.0000x reference)
//
#include <hip/hip_runtime.h>

// LSTM: B=4096, T=2048, F=1, H=3. Output h_T [4096,3] fp32.
//
// R3: 275 cyc/step, VALUBusy 40% -> ~110 issue cyc + ~165 exposed dep
// latency on the serial recurrence chain; ~100 cyc/step were the 4
// transcendentals (exp2+rcp x2 blocks, ~26 cyc each incl issue-block).
// R4: rational Pade[5/5] tanh with med3 clamp -> 2 trans/step (rcp only),
// one trans-block per activation on the path; sigmoid = 0.5+0.5*tanh(x/2)
// with the /2 folded into pre-scaled per-lane weights; num/den in
// parallel, a*N overlaps rcp. Same 16-lane/element DPP layout (1024
// waves = every SIMD active).
//
// tanh(x) ~ x(945+105z+z^2)/(945+420z+15z^2), z=x^2; med3 clamp handles
// |x| large (ratio -> x/15 grows, clamp restores +-1). Max err ~1.3e-3
// near |x|~3.7; damped by f~0.5 over steps -> final ~2e-3 < 7.2e-3 thr.

#define T_LEN 2048
#define BATCH 4096

template <int CTRL, int RMASK, int BMASK, bool BC>
__device__ __forceinline__ float dppf(float oldv, float src) {
    int r = __builtin_amdgcn_update_dpp(__float_as_int(oldv), __float_as_int(src),
                                        CTRL, RMASK, BMASK, BC);
    return __int_as_float(r);
}

__global__ __launch_bounds__(64, 1) void lstm_kernel(
    const float* __restrict__ X,
    const float* __restrict__ Wih,   // [12,1]
    const float* __restrict__ Whh,   // [12,3]
    const float* __restrict__ bih,   // [12]
    const float* __restrict__ bhh,   // [12]
    float* __restrict__ out)         // [4096,3]
{
    const int lane = threadIdx.x;        // block = 1 wave of 64
    const int row  = lane >> 4;          // element slot within wave (DPP row)
    const int l16  = lane & 15;
    const int gt   = l16 >> 2;           // 0:i 1:f 2:g 3:o  (DPP bank)
    const int u3   = l16 & 3;
    const int u    = (u3 < 3) ? u3 : 2;  // hidden unit; slot 3 duplicates 2
    const int e    = blockIdx.x * 4 + row;
    const int gate = 3 * gt + u;         // torch rows: i 0-2, f 3-5, g 6-8, o 9-11

    // Input prescale folded into weights: sigmoid lanes evaluate tanh(x/2).
    const bool isg = (gt == 2);
    const float ws = isg ? 1.0f : 0.5f;

    const float wx = Wih[gate] * ws;
    const float bb = (bih[gate] + bhh[gate]) * ws;
    const float w0 = Whh[gate * 3 + 0] * ws;
    const float w1 = Whh[gate * 3 + 1] * ws;
    const float w2 = Whh[gate * 3 + 2] * ws;

    // Uniform activation tail: v = med3(fma(mm, P, aa), lo, 1.0)
    //   sigmoid lanes: mm=0.5 aa=0.5 lo=0   (0.5+0.5*tanh(x/2), clamp [0,1])
    //   g lanes:       mm=1.0 aa=0.0 lo=-1  (tanh(x), clamp [-1,1])
    const float mm = isg ? 1.0f : 0.5f;
    const float aa = isg ? 0.0f : 0.5f;
    const float lo = isg ? -1.0f : 0.0f;

    // All 16 lanes of a row load the same float4 (HW same-address broadcast).
    const float4* xp = (const float4*)(X + (size_t)e * T_LEN);
    constexpr int T4 = T_LEN / 4;
    float4 b0 = xp[0];
    float4 b1 = xp[1];
    float4 b2 = xp[2];

    float h = 0.f, c = 0.f;
    float h0 = 0.f, h1 = 0.f, h2 = 0.f;

    for (int t4 = 0; t4 < T4; ++t4) {
        int nidx = t4 + 3;
        nidx = nidx < T4 ? nidx : T4 - 1;
        float4 nb = xp[nidx];

        // x-contribution (pre-scaled): independent of h, fills stall slots.
        float xa[4];
        xa[0] = __builtin_fmaf(b0.x, wx, bb);
        xa[1] = __builtin_fmaf(b0.y, wx, bb);
        xa[2] = __builtin_fmaf(b0.z, wx, bb);
        xa[3] = __builtin_fmaf(b0.w, wx, bb);

#pragma unroll
        for (int s = 0; s < 4; ++s) {
            // gate preactivation (pre-scaled for sigmoid lanes)
            float a = __builtin_fmaf(h0, w0, xa[s]);
            a = __builtin_fmaf(h1, w1, a);
            a = __builtin_fmaf(h2, w2, a);

            // rational tanh core: P = a*N(z)*rcp(D(z)), z=a^2
            float z  = a * a;
            float nn = __builtin_fmaf(z, z + 105.0f, 945.0f);
            float dd = __builtin_fmaf(z, __builtin_fmaf(z, 15.0f, 420.0f), 945.0f);
            float rr = __builtin_amdgcn_rcpf(dd);
            float an = a * nn;                    // overlaps the rcp
            float P  = an * rr;
            float q  = __builtin_fmaf(mm, P, aa);
            float v  = __builtin_amdgcn_fmed3f(q, lo, 1.0f);

            // gather f,g,o values onto the unit quad (lanes 0-3 of the row)
            float vf = dppf<0x104, 0xF, 0xF, true>(0.f, v);  // row_shl:4
            float vg = dppf<0x108, 0xF, 0xF, true>(0.f, v);  // row_shl:8
            float vo = dppf<0x10C, 0xF, 0xF, true>(0.f, v);  // row_shl:12

            // c update (valid on lanes 0-3; other lanes compute garbage)
            c = __builtin_fmaf(vf, c, v * vg);

            // tanh(c), rational + clamp
            float z2 = c * c;
            float n2 = __builtin_fmaf(z2, z2 + 105.0f, 945.0f);
            float d2 = __builtin_fmaf(z2, __builtin_fmaf(z2, 15.0f, 420.0f), 945.0f);
            float r2 = __builtin_amdgcn_rcpf(d2);
            float cn = c * n2;                    // overlaps the rcp
            float P2 = cn * r2;
            float T  = __builtin_amdgcn_fmed3f(P2, -1.0f, 1.0f);
            h = vo * T;

            // replicate h quad0 across the row, then quad-broadcast h0,h1,h2
            h = dppf<0x114, 0xF, 0x2, false>(h, h);  // row_shr:4 -> bank 1
            h = dppf<0x118, 0xF, 0xC, false>(h, h);  // row_shr:8 -> banks 2,3
            h0 = dppf<0x00, 0xF, 0xF, true>(0.f, h); // quad_perm slot0
            h1 = dppf<0x55, 0xF, 0xF, true>(0.f, h); // quad_perm slot1
            h2 = dppf<0xAA, 0xF, 0xF, true>(0.f, h); // quad_perm slot2
        }
        b0 = b1; b1 = b2; b2 = nb;
    }

    if (l16 < 3) out[(size_t)e * 3 + l16] = h;
}

extern "C" void kernel_launch(void* const* d_in, const int* in_sizes, int n_in,
                              void* d_out, int out_size, void* d_ws, size_t ws_size,
                              hipStream_t stream) {
    const float* X   = (const float*)d_in[0];
    const float* Wih = (const float*)d_in[1];
    const float* Whh = (const float*)d_in[2];
    const float* bih = (const float*)d_in[3];
    const float* bhh = (const float*)d_in[4];
    float* out = (float*)d_out;

    // 4096 elements x 16 lanes = 65536 threads = 1024 waves = 1 per SIMD.
    dim3 grid(BATCH / 4);
    dim3 block(64);
    lstm_kernel<<<grid, block, 0, stream>>>(X, Wih, Whh, bih, bhh, out);
}

// Round 5
// 239.953 us; speedup vs baseline: 1.1825x; 1.1825x over previous
//
#include <hip/hip_runtime.h>

// LSTM: B=4096, T=2048, F=1, H=3. Output h_T [4096,3] fp32.
//
// Cost model fitted from R3/R4: wall/step ~= 2*(#full-rate instrs) +
// ~8*(#transcendental instrs). Pure issue-bound; dep stalls ~free; trans
// (exp2/rcp) are quarter-rate (8 cyc issue per wave64). exp2-form
// activation (2F+2T=18cyc) beats Pade (8F+1T=23cyc) -> revert to exp2.
// R5 trims F: fold activation input scales into the per-lane weights
// (exact): sigma lanes' weights *= -log2e; g lane's *= -2log2e and its
// am/ad emit gs = -2log2e*tanh directly, so cell state is kept scaled
// (cs = -2log2e*c) and tanh(c) = fma(2, rcp(1+exp2(cs)), -1).
// Deletes both pre-exp2 muls (-16 cyc/step). 8-substep unroll halves
// loop overhead. Layout unchanged: 16 lanes/elem (lane=4*gt+u),
// 4 elem/wave, 1024 waves = every SIMD active.

#define T_LEN 2048
#define BATCH 4096

template <int CTRL, int RMASK, int BMASK, bool BC>
__device__ __forceinline__ float dppf(float oldv, float src) {
    int r = __builtin_amdgcn_update_dpp(__float_as_int(oldv), __float_as_int(src),
                                        CTRL, RMASK, BMASK, BC);
    return __int_as_float(r);
}

__global__ __launch_bounds__(64, 1) void lstm_kernel(
    const float* __restrict__ X,
    const float* __restrict__ Wih,   // [12,1]
    const float* __restrict__ Whh,   // [12,3]
    const float* __restrict__ bih,   // [12]
    const float* __restrict__ bhh,   // [12]
    float* __restrict__ out)         // [4096,3]
{
    const int lane = threadIdx.x;        // block = 1 wave of 64
    const int row  = lane >> 4;          // element slot within wave (DPP row)
    const int l16  = lane & 15;
    const int gt   = l16 >> 2;           // 0:i 1:f 2:g 3:o  (DPP bank)
    const int u3   = l16 & 3;
    const int u    = (u3 < 3) ? u3 : 2;  // hidden unit; slot 3 duplicates 2
    const int e    = blockIdx.x * 4 + row;
    const int gate = 3 * gt + u;         // torch rows: i 0-2, f 3-5, g 6-8, o 9-11

    // Scale folding (exact):
    //   sigma lanes (i,f,o): a' = -log2e * A  -> sigma(A) = rcp(1+exp2(a'))
    //   g lane:              a' = -2log2e * A -> gs = -2log2e*tanh(A)
    //                        = fma(-4log2e, rcp(1+exp2(a')), 2log2e)
    const bool isg = (gt == 2);
    const float SC = isg ? -2.88539008177792681472f : -1.44269504088896340736f;

    const float wx = Wih[gate] * SC;
    const float bb = (bih[gate] + bhh[gate]) * SC;
    const float w0 = Whh[gate * 3 + 0] * SC;
    const float w1 = Whh[gate * 3 + 1] * SC;
    const float w2 = Whh[gate * 3 + 2] * SC;

    const float am = isg ? -5.77078016355585362944f : 1.0f;
    const float ad = isg ?  2.88539008177792681472f : 0.0f;

    // All 16 lanes of a row load the same float4 (HW same-address broadcast).
    const float4* xp = (const float4*)(X + (size_t)e * T_LEN);
    constexpr int T8 = T_LEN / 8;        // 256 iters, 8 substeps each

    // 3-pair-deep rolling prefetch (~16-24 substeps ahead).
    float4 a0 = xp[0], a1 = xp[1];
    float4 b0 = xp[2], b1 = xp[3];
    float4 c0 = xp[4], c1 = xp[5];

    float h = 0.f, cs = 0.f;             // cs = -2log2e * c (scaled cell)
    float h0 = 0.f, h1 = 0.f, h2 = 0.f;

    for (int t8 = 0; t8 < T8; ++t8) {
        int nidx = 2 * t8 + 6;
        nidx = nidx < 2 * T8 - 2 ? nidx : 2 * T8 - 2;  // clamp (reload tail)
        float4 n0 = xp[nidx];
        float4 n1 = xp[nidx + 1];

        // x-contributions (pre-scaled): independent of h, fill stall slots.
        float xa[8];
        xa[0] = __builtin_fmaf(a0.x, wx, bb);
        xa[1] = __builtin_fmaf(a0.y, wx, bb);
        xa[2] = __builtin_fmaf(a0.z, wx, bb);
        xa[3] = __builtin_fmaf(a0.w, wx, bb);
        xa[4] = __builtin_fmaf(a1.x, wx, bb);
        xa[5] = __builtin_fmaf(a1.y, wx, bb);
        xa[6] = __builtin_fmaf(a1.z, wx, bb);
        xa[7] = __builtin_fmaf(a1.w, wx, bb);

#pragma unroll
        for (int s = 0; s < 8; ++s) {
            // gate preactivation (already in scaled space)
            float a = __builtin_fmaf(h0, w0, xa[s]);
            a = __builtin_fmaf(h1, w1, a);
            a = __builtin_fmaf(h2, w2, a);

            // activation: r = rcp(1+exp2(a)); v = fma(am, r, ad)
            //   i,f,o lanes: v = sigma(A);  g lane: v = -2log2e*tanh(A)
            float ee = __builtin_amdgcn_exp2f(a);
            float rr = __builtin_amdgcn_rcpf(1.0f + ee);
            float v  = __builtin_fmaf(am, rr, ad);

            // gather f,g,o values onto the unit quad (lanes 0-3 of the row)
            float vf = dppf<0x104, 0xF, 0xF, true>(0.f, v);  // row_shl:4
            float vg = dppf<0x108, 0xF, 0xF, true>(0.f, v);  // row_shl:8
            float vo = dppf<0x10C, 0xF, 0xF, true>(0.f, v);  // row_shl:12

            // scaled cell update (valid on lanes 0-3)
            cs = __builtin_fmaf(vf, cs, v * vg);

            // tanh(c) = fma(2, rcp(1+exp2(cs)), -1)   (cs already scaled)
            float e2 = __builtin_amdgcn_exp2f(cs);
            float r2 = __builtin_amdgcn_rcpf(1.0f + e2);
            float T  = __builtin_fmaf(2.0f, r2, -1.0f);
            h = vo * T;

            // replicate h quad0 across the row, then quad-broadcast h0,h1,h2
            h = dppf<0x114, 0xF, 0x2, false>(h, h);  // row_shr:4 -> bank 1
            h = dppf<0x118, 0xF, 0xC, false>(h, h);  // row_shr:8 -> banks 2,3
            h0 = dppf<0x00, 0xF, 0xF, true>(0.f, h); // quad_perm slot0
            h1 = dppf<0x55, 0xF, 0xF, true>(0.f, h); // quad_perm slot1
            h2 = dppf<0xAA, 0xF, 0xF, true>(0.f, h); // quad_perm slot2
        }
        a0 = b0; a1 = b1;
        b0 = c0; b1 = c1;
        c0 = n0; c1 = n1;
    }

    if (l16 < 3) out[(size_t)e * 3 + l16] = h;
}

extern "C" void kernel_launch(void* const* d_in, const int* in_sizes, int n_in,
                              void* d_out, int out_size, void* d_ws, size_t ws_size,
                              hipStream_t stream) {
    const float* X   = (const float*)d_in[0];
    const float* Wih = (const float*)d_in[1];
    const float* Whh = (const float*)d_in[2];
    const float* bih = (const float*)d_in[3];
    const float* bhh = (const float*)d_in[4];
    float* out = (float*)d_out;

    // 4096 elements x 16 lanes = 65536 threads = 1024 waves = 1 per SIMD.
    dim3 grid(BATCH / 4);
    dim3 block(64);
    lstm_kernel<<<grid, block, 0, stream>>>(X, Wih, Whh, bih, bhh, out);
}